// Round 3
// baseline (148.794 us; speedup 1.0000x reference)
//
#include <hip/hip_runtime.h>

// OccupancyGridForestAS: per-point voxel lookup in a forest of 64 dense 64^3 grids,
// addressed via an 8^3 block->tree lookup table.
//
// Inputs (setup_inputs order):
//   d_in[0]: pts            float32 [4194304, 3]   (48 MiB, streamed)
//   d_in[1]: occ_val_grid   float32 [64, 64, 64, 64] (64 MiB, random 4B gathers)
//   d_in[2]: block_lookup   int32   [8, 8, 8]      (2 KiB)
// Output: float32 [4194304] (16 MiB, streamed)
//
// R5 -> R6 (post-mortem of R5): fire-and-forget sweep REGRESSED (45-50 us,
// FETCH 90->105 MB). Mechanism: without any ordering, gathers race AHEAD of
// the sweep -> miss L3 cold (random-access HBM fetch) AND the sweep refetches
// the same lines sequentially = double traffic, no benefit. R0's consumed
// prefetch worked precisely BECAUSE its serialization ordered sweep-before-
// gather; it just paid with 3 dependent HBM round trips per wave (2.55 TB/s).
//
// R6: stream-ordered two-kernel pipeline -- the clean form of that ordering.
//  * Kernel 1: pure sequential sweep of the 64 MB grid into L3 (consumed
//    loads + asm keepalive, the R0-proven pattern). Pure streaming kernel,
//    ~6.3-6.5 TB/s like the harness's fill kernel -> ~10 us.
//  * Kernel 2: the R4 kernel unchanged (nt pts loads, early barrier, LDS lut,
//    8 independent gathers, nt stores). Its only weakness was cold gathers;
//    stream ordering guarantees the grid is fully L3-resident now -> gathers
//    are ~400-cyc L3 hits, hidden under the 48+16 MB stream -> ~12-15 us.
//  * No cooperative-launch risk; the stream IS the grid-wide barrier.

#define LDIM 8
#define RES  64
#define PPT  8   // points per thread

typedef float v4f __attribute__((ext_vector_type(4)));

// --- Kernel 1: L3 sweep of the grid. 2048 blocks x 256 threads x 8 x 16B = 64 MiB.
__global__ __launch_bounds__(256) void sweep_kernel(
    const v4f* __restrict__ g4, int n)   // n = total threads = stride in v4f units
{
    int j = blockIdx.x * blockDim.x + threadIdx.x;
    float acc = 0.0f;
#pragma unroll
    for (int s = 0; s < 8; ++s) {
        v4f t = g4[j + s * n];
        acc += t.x + t.y + t.z + t.w;
    }
    asm volatile("" :: "v"(acc));  // keep the sweep alive; nothing stored
}

// --- Kernel 2: the point lookup (R4 structure).
__global__ __launch_bounds__(256, 8) void occ_forest_kernel(
    const v4f*    __restrict__ pts4,
    const float*  __restrict__ grid,
    const int*    __restrict__ lookup,
    v4f*          __restrict__ out4,
    int n8)       // number of 8-point groups (= total threads)
{
    __shared__ int slut[LDIM * LDIM * LDIM];  // 512 ints = 2 KB

    // Stage lookup table into LDS (coalesced int2 loads).
    {
        const int2* lk2 = (const int2*)lookup;
        int2* sl2 = (int2*)slut;
        sl2[threadIdx.x] = lk2[threadIdx.x];  // 256 threads x 8B = 2 KB
    }
    // Barrier BEFORE any global load: its vmcnt(0)+lgkmcnt(0) drain only waits
    // on the 8B LDS store above (trivial), not on in-flight HBM loads.
    __syncthreads();

    int j = blockIdx.x * blockDim.x + threadIdx.x;

    // 8 points = 24 floats = 6 float4s, fully coalesced, nontemporal (read-once:
    // don't evict grid lines from L3).
    const v4f* p = pts4 + 6 * j;
    v4f q0 = __builtin_nontemporal_load(p + 0);
    v4f q1 = __builtin_nontemporal_load(p + 1);
    v4f q2 = __builtin_nontemporal_load(p + 2);
    v4f q3 = __builtin_nontemporal_load(p + 3);
    v4f q4 = __builtin_nontemporal_load(p + 4);
    v4f q5 = __builtin_nontemporal_load(p + 5);

    float px[PPT] = {q0.x, q0.w, q1.z, q2.y, q3.x, q3.w, q4.z, q5.y};
    float py[PPT] = {q0.y, q1.x, q1.w, q2.z, q3.y, q4.x, q4.w, q5.z};
    float pz[PPT] = {q0.z, q1.y, q2.x, q2.w, q3.z, q4.y, q5.x, q5.w};

    int  idx[PPT];
    bool valid[PPT];

    // Phase 1: pure ALU -- compute all gather indices (0 for invalid lanes so
    // they coalesce into a single broadcast line hit).
#pragma unroll
    for (int k = 0; k < PPT; ++k) {
        float x = px[k], y = py[k], z = pz[k];

        int bx = (int)floorf(x);
        int by = (int)floorf(y);
        int bz = (int)floorf(z);
        bool in_dom = (bx >= 0) & (bx < LDIM) &
                      (by >= 0) & (by < LDIM) &
                      (bz >= 0) & (bz < LDIM);
        int cx = min(max(bx, 0), LDIM - 1);
        int cy = min(max(by, 0), LDIM - 1);
        int cz = min(max(bz, 0), LDIM - 1);

        int bidx = slut[(cx * LDIM + cy) * LDIM + cz];
        bool v = in_dom & (bidx >= 0);

        // Reference float op sequence, replicated exactly:
        // block_x = 2*(p - bcs) - 1 ; t = (block_x*0.5 + 0.5)*res ; vox = clip(floor(t),0,res-1)
        float bxf = 2.0f * (x - (float)cx) - 1.0f;
        float byf = 2.0f * (y - (float)cy) - 1.0f;
        float bzf = 2.0f * (z - (float)cz) - 1.0f;
        float tx = (bxf * 0.5f + 0.5f) * (float)RES;
        float ty = (byf * 0.5f + 0.5f) * (float)RES;
        float tz = (bzf * 0.5f + 0.5f) * (float)RES;
        int vx = min(max((int)floorf(tx), 0), RES - 1);
        int vy = min(max((int)floorf(ty), 0), RES - 1);
        int vz = min(max((int)floorf(tz), 0), RES - 1);

        int sb = v ? bidx : 0;
        int ii = ((sb * RES + vx) * RES + vy) * RES + vz;  // < 2^24
        idx[k]   = v ? ii : 0;   // invalid -> grid[0]: same-line broadcast, ~free
        valid[k] = v;
    }

    // Phase 2: 8 independent unconditional gathers -- all L3 hits now that the
    // sweep kernel has completed (stream ordering). All in flight at once.
    float vals[PPT];
#pragma unroll
    for (int k = 0; k < PPT; ++k) {
        vals[k] = grid[idx[k]];
    }

    // Phase 3: select + coalesced nontemporal store.
#pragma unroll
    for (int k = 0; k < PPT; ++k) {
        vals[k] = valid[k] ? vals[k] : 0.0f;
    }

    v4f o0 = {vals[0], vals[1], vals[2], vals[3]};
    v4f o1 = {vals[4], vals[5], vals[6], vals[7]};
    __builtin_nontemporal_store(o0, out4 + 2 * j + 0);
    __builtin_nontemporal_store(o1, out4 + 2 * j + 1);
}

extern "C" void kernel_launch(void* const* d_in, const int* in_sizes, int n_in,
                              void* d_out, int out_size, void* d_ws, size_t ws_size,
                              hipStream_t stream) {
    const float* pts    = (const float*)d_in[0];
    const float* grid   = (const float*)d_in[1];
    const int*   lookup = (const int*)d_in[2];
    float*       out    = (float*)d_out;

    // out_size = 4194304, divisible by 8; 8 points per thread.
    int n8 = out_size / PPT;                    // 524288 threads
    int threads = 256;
    int blocks = (n8 + threads - 1) / threads;  // 2048 blocks

    // Kernel 1: pull the whole 64 MiB grid into L3 at sequential-stream BW.
    sweep_kernel<<<blocks, threads, 0, stream>>>((const v4f*)grid, n8);

    // Kernel 2: the lookup; stream ordering guarantees L3-warm gathers.
    occ_forest_kernel<<<blocks, threads, 0, stream>>>(
        (const v4f*)pts, grid, lookup, (v4f*)out, n8);
}

// Round 4
// 135.282 us; speedup vs baseline: 1.0999x; 1.0999x over previous
//
#include <hip/hip_runtime.h>

// OccupancyGridForestAS: per-point voxel lookup in a forest of 64 dense 64^3 grids,
// addressed via an 8^3 block->tree lookup table.
//
// Inputs (setup_inputs order):
//   d_in[0]: pts            float32 [4194304, 3]   (48 MiB, streamed)
//   d_in[1]: occ_val_grid   float32 [64, 64, 64, 64] (64 MiB, random 4B gathers)
//   d_in[2]: block_lookup   int32   [8, 8, 8]      (2 KiB)
// Output: float32 [4194304] (16 MiB, streamed)
//
// R6 -> R7 post-mortem triangulation (R0=42.6, R4=45.3, R5=45.0, R6=46.6 us/iter):
//  * R6's globally-ordered sweep gave L3-warm gathers, yet its main kernel still
//    ran ~34 us for ~64 MB of PURE streams (~2 TB/s) -- 3x slower than the
//    harness fill kernel (6.5 TB/s). L3 warming is a ~2.7 us side-show.
//  * Common limiter across ALL variants: two dependent load phases in lockstep.
//    Every wave issues 6 pts loads -> full-drain wait -> ALU (HBM idle) ->
//    8 gathers -> wait. VALUBusy 12.6% + HBM 32% ~= 45%; the rest is bubbles
//    where no wave has memory in flight.
//
// R7: software pipeline, 2 iterations x 4 points per thread.
//  * All 6 pts loads issue up front, but idx-A needs only a0..a2 (partial
//    vmcnt wait); A-gathers fly while b0..b2 land; idx-B ALU overlaps A-gather
//    latency; B-gathers issue before store-A waits (vmcnt(4)). The wave always
//    has memory in flight -> bubbles collapse.
//  * No sweep this round (isolate the pipelining lever; re-add fused sweep if
//    FETCH shows cold-gather cost dominating).
//  * Kept: LDS lut + early barrier (free vmcnt drain), nt pts loads / out
//    stores (read/write-once; don't evict grid lines), 2048 blocks co-resident.

#define LDIM 8
#define RES  64

typedef float v4f __attribute__((ext_vector_type(4)));

// Compute gather indices for 4 points packed in 3 float4s.
__device__ __forceinline__ void compute_idx4(
    const int* __restrict__ slut, v4f q0, v4f q1, v4f q2,
    int idx[4], bool valid[4])
{
    const float xs[4] = {q0.x, q0.w, q1.z, q2.y};
    const float ys[4] = {q0.y, q1.x, q1.w, q2.z};
    const float zs[4] = {q0.z, q1.y, q2.x, q2.w};
#pragma unroll
    for (int k = 0; k < 4; ++k) {
        float x = xs[k], y = ys[k], z = zs[k];

        int bx = (int)floorf(x);
        int by = (int)floorf(y);
        int bz = (int)floorf(z);
        bool in_dom = (bx >= 0) & (bx < LDIM) &
                      (by >= 0) & (by < LDIM) &
                      (bz >= 0) & (bz < LDIM);
        int cx = min(max(bx, 0), LDIM - 1);
        int cy = min(max(by, 0), LDIM - 1);
        int cz = min(max(bz, 0), LDIM - 1);

        int bidx = slut[(cx * LDIM + cy) * LDIM + cz];
        bool v = in_dom & (bidx >= 0);

        // Reference float op sequence, replicated exactly:
        // block_x = 2*(p - bcs) - 1 ; t = (block_x*0.5 + 0.5)*res ; vox = clip(floor(t),0,res-1)
        float bxf = 2.0f * (x - (float)cx) - 1.0f;
        float byf = 2.0f * (y - (float)cy) - 1.0f;
        float bzf = 2.0f * (z - (float)cz) - 1.0f;
        float tx = (bxf * 0.5f + 0.5f) * (float)RES;
        float ty = (byf * 0.5f + 0.5f) * (float)RES;
        float tz = (bzf * 0.5f + 0.5f) * (float)RES;
        int vx = min(max((int)floorf(tx), 0), RES - 1);
        int vy = min(max((int)floorf(ty), 0), RES - 1);
        int vz = min(max((int)floorf(tz), 0), RES - 1);

        int sb = v ? bidx : 0;
        int ii = ((sb * RES + vx) * RES + vy) * RES + vz;  // < 2^24
        idx[k]   = v ? ii : 0;   // invalid -> grid[0]: same-line broadcast, ~free
        valid[k] = v;
    }
}

__global__ __launch_bounds__(256, 8) void occ_forest_kernel(
    const v4f*    __restrict__ pts4,
    const float*  __restrict__ grid,
    const int*    __restrict__ lookup,
    v4f*          __restrict__ out4,
    int T)        // total threads; each handles 4-point groups j and j+T
{
    __shared__ int slut[LDIM * LDIM * LDIM];  // 512 ints = 2 KB

    // Stage lookup table into LDS (coalesced int2 loads).
    {
        const int2* lk2 = (const int2*)lookup;
        ((int2*)slut)[threadIdx.x] = lk2[threadIdx.x];  // 256 x 8B = 2 KB
    }
    // Barrier BEFORE any global load: its vmcnt(0) drain costs nothing.
    __syncthreads();

    int j = blockIdx.x * blockDim.x + threadIdx.x;

    // Issue ALL pts loads up front: 6 coalesced nt dwordx4 (A then B).
    const v4f* pA = pts4 + 3 * j;
    v4f a0 = __builtin_nontemporal_load(pA + 0);
    v4f a1 = __builtin_nontemporal_load(pA + 1);
    v4f a2 = __builtin_nontemporal_load(pA + 2);
    const v4f* pB = pts4 + 3 * (j + T);
    v4f b0 = __builtin_nontemporal_load(pB + 0);
    v4f b1 = __builtin_nontemporal_load(pB + 1);
    v4f b2 = __builtin_nontemporal_load(pB + 2);

    // --- Iteration A: idx needs only a0..a2 (partial vmcnt wait). ---
    int  idxA[4];  bool valA[4];
    compute_idx4(slut, a0, a1, a2, idxA, valA);

    // A-gathers in flight while b0..b2 are still landing.
    float vA[4];
#pragma unroll
    for (int k = 0; k < 4; ++k) vA[k] = grid[idxA[k]];

    // --- Iteration B ALU: overlaps A-gather latency (b* landed meanwhile). ---
    int  idxB[4];  bool valB[4];
    compute_idx4(slut, b0, b1, b2, idxB, valB);

    // B-gathers issue BEFORE we wait on A-gathers.
    float vB[4];
#pragma unroll
    for (int k = 0; k < 4; ++k) vB[k] = grid[idxB[k]];

    // Store A: waits vmcnt(4) only (B-gathers remain in flight).
#pragma unroll
    for (int k = 0; k < 4; ++k) vA[k] = valA[k] ? vA[k] : 0.0f;
    v4f oA = {vA[0], vA[1], vA[2], vA[3]};
    __builtin_nontemporal_store(oA, out4 + j);

    // Store B.
#pragma unroll
    for (int k = 0; k < 4; ++k) vB[k] = valB[k] ? vB[k] : 0.0f;
    v4f oB = {vB[0], vB[1], vB[2], vB[3]};
    __builtin_nontemporal_store(oB, out4 + j + T);
}

extern "C" void kernel_launch(void* const* d_in, const int* in_sizes, int n_in,
                              void* d_out, int out_size, void* d_ws, size_t ws_size,
                              hipStream_t stream) {
    const float* pts    = (const float*)d_in[0];
    const float* grid   = (const float*)d_in[1];
    const int*   lookup = (const int*)d_in[2];
    float*       out    = (float*)d_out;

    // out_size = 4194304 points; 8 points per thread as 2 pipelined groups of 4.
    int T = out_size / 8;                       // 524288 threads
    int threads = 256;
    int blocks = (T + threads - 1) / threads;   // 2048 blocks = 8/CU, co-resident
    occ_forest_kernel<<<blocks, threads, 0, stream>>>(
        (const v4f*)pts, grid, lookup, (v4f*)out, T);
}